// Round 3
// baseline (562.708 us; speedup 1.0000x reference)
//
#include <hip/hip_runtime.h>

// Fused actor-critic forward for S=256,B=1024,D=64,H=128,A=8.
// R2: no weight LDS at all — prep packs weights as bf16 fragment-ordered
// images (64x16B chunks per wave-load burst); waves are feature-split
// (wave w owns feats w*32..w*32+31), weights go global(L2)->VGPR directly.
// Single 32KB LDS activation buffer (X -> H1 -> H2 -> h). cvt_pk bf16 packs.

#define NROWS (256 * 1024)
#define HID 128
#define ACTD 8

// ws layout (bytes)
#define W1_OFF 0                  // [128][64]  frag-img 16KB
#define W2_OFF 16384              // [128][128] frag-img 32KB
#define WI_OFF 49152              // wih rows 0..127   32KB
#define WG_OFF 81920              // wih rows 256..383 32KB
#define WO_OFF 114688             // wih rows 384..511 32KB
#define PSTR 147456               // per-path stride
#define HEAD_OFF (2 * PSTR)       // actor [mw;lw] 4KB, critic [vw;0] 4KB
#define GB_OFF (HEAD_OFF + 8192)  // combined bih+bhh, 512 f32 per path

typedef __attribute__((ext_vector_type(8))) short s16x8;
typedef __attribute__((ext_vector_type(4))) float fx4;
typedef __attribute__((ext_vector_type(2))) unsigned int u32x2;
typedef __attribute__((ext_vector_type(4))) unsigned int u32x4;

__device__ __forceinline__ unsigned int cvtpk(float lo, float hi) {
  unsigned int r;
  asm("v_cvt_pk_bf16_f32 %0, %1, %2" : "=v"(r) : "v"(lo), "v"(hi));
  return r;
}

__device__ __forceinline__ float fsig(float x) {
  return __builtin_amdgcn_rcpf(1.0f + __expf(-x));
}
__device__ __forceinline__ float ftanh(float x) {
  return 2.0f * __builtin_amdgcn_rcpf(1.0f + __expf(-2.0f * x)) - 1.0f;
}

// 8 bf16 from swizzled LDS act tile: row-major, 2^rowsh bytes/row,
// chunk XOR (row&7)<<4.
__device__ __forceinline__ s16x8 frag_ld(const unsigned short* base, int row,
                                         int kbyte, int rowsh) {
  int byte = (row << rowsh) + (kbyte ^ ((row & 7) << 4));
  return *(const s16x8*)((const char*)base + byte);
}

__device__ __forceinline__ void zacc(fx4 acc[8][2]) {
#pragma unroll
  for (int j = 0; j < 8; ++j)
#pragma unroll
    for (int i = 0; i < 2; ++i) acc[j][i] = fx4{0.f, 0.f, 0.f, 0.f};
}

// Feature-split GEMM: wave wv computes feats wv*32..+31 for all 128 rows.
// Weights from frag-ordered global image: 1KB block per (featTile16, kc),
// laid out [ks:4][r:16][16B] so a wave load is one contiguous burst.
template <int KC, int ASH>
__device__ __forceinline__ void gemm_f(const char* wimg,
                                       const unsigned short* at, int wv,
                                       int lane, fx4 acc[8][2]) {
  const int l15 = lane & 15;
  const int kb0 = (lane >> 4) << 4;
  const int woff = ((lane >> 4) << 8) + (l15 << 4);
#pragma unroll
  for (int kc = 0; kc < KC; ++kc) {
    s16x8 w0 = *(const s16x8*)(wimg + (((wv * 2 + 0) * KC + kc) << 10) + woff);
    s16x8 w1 = *(const s16x8*)(wimg + (((wv * 2 + 1) * KC + kc) << 10) + woff);
#pragma unroll
    for (int jt = 0; jt < 8; ++jt) {
      s16x8 a = frag_ld(at, jt * 16 + l15, kc * 64 + kb0, ASH);
      acc[jt][0] = __builtin_amdgcn_mfma_f32_16x16x32_bf16(w0, a, acc[jt][0], 0, 0, 0);
      acc[jt][1] = __builtin_amdgcn_mfma_f32_16x16x32_bf16(w1, a, acc[jt][1], 0, 0, 0);
    }
  }
}

// acc + bias -> (relu) -> bf16 -> swizzled abuf [row][feat] 256B rows
template <bool RELU>
__device__ __forceinline__ void epi(fx4 acc[8][2], const float* __restrict__ b0,
                                    const float* __restrict__ b1w,
                                    unsigned short* obuf, int fb, int lane) {
  const int g4 = (lane >> 4) << 2;
  const int l15 = lane & 15;
  char* ob = (char*)obuf;
#pragma unroll
  for (int it = 0; it < 2; ++it) {
    int n0 = fb + it * 16 + g4;
    fx4 bv = *(const fx4*)((it ? b1w : b0) + (it ? n0 : n0));
#pragma unroll
    for (int jt = 0; jt < 8; ++jt) {
      fx4 v = acc[jt][it] + bv;
      if (RELU) {
#pragma unroll
        for (int r = 0; r < 4; ++r) v[r] = fmaxf(v[r], 0.0f);
      }
      u32x2 u;
      u[0] = cvtpk(v[0], v[1]);
      u[1] = cvtpk(v[2], v[3]);
      int m = jt * 16 + l15;
      *(u32x2*)(ob + (m << 8) + ((n0 * 2) ^ ((m & 7) << 4))) = u;
    }
  }
}

// ---------------- prep: weights -> bf16 fragment-ordered images ------------
__global__ void prep_weights(const float* __restrict__ aw1,
                             const float* __restrict__ aw2,
                             const float* __restrict__ awih,
                             const float* __restrict__ cw1,
                             const float* __restrict__ cw2,
                             const float* __restrict__ cwih,
                             const float* __restrict__ mw,
                             const float* __restrict__ lw,
                             const float* __restrict__ vw,
                             const float* __restrict__ abih,
                             const float* __restrict__ abhh,
                             const float* __restrict__ cbih,
                             const float* __restrict__ cbhh,
                             char* __restrict__ ws) {
  int y = blockIdx.y;
  int idx = blockIdx.x * 256 + threadIdx.x;
  if (y >= 12) {  // combined gate biases (f32)
    if (idx < 512) {
      float* dst = (float*)(ws + GB_OFF + (size_t)(y - 12) * 2048);
      const float* b0 = (y == 12) ? abih : cbih;
      const float* b1 = (y == 12) ? abhh : cbhh;
      dst[idx] = b0[idx] + b1[idx];
    }
    return;
  }
  if (y >= 10) {  // head images: 16 rows x 128 cols
    if (idx >= 256) return;
    int row = idx >> 4, c16 = idx & 15, kc = c16 >> 2, ks = c16 & 3;
    fx4 v0 = {0.f, 0.f, 0.f, 0.f}, v1 = v0;
    if (y == 10) {
      const float* src = (row < 8) ? (mw + (size_t)row * HID + c16 * 8)
                                   : (lw + (size_t)(row - 8) * HID + c16 * 8);
      v0 = ((const fx4*)src)[0];
      v1 = ((const fx4*)src)[1];
    } else if (row == 0) {
      const float* src = vw + c16 * 8;
      v0 = ((const fx4*)src)[0];
      v1 = ((const fx4*)src)[1];
    }
    u32x4 u;
    u[0] = cvtpk(v0[0], v0[1]);
    u[1] = cvtpk(v0[2], v0[3]);
    u[2] = cvtpk(v1[0], v1[1]);
    u[3] = cvtpk(v1[2], v1[3]);
    int dst = ((kc * 4 + ks) * 16 + row) * 16;
    *(u32x4*)(ws + HEAD_OFF + (size_t)(y - 10) * 4096 + dst) = u;
    return;
  }
  const float* src;
  int nch, ksh, KC, off;
  switch (y) {
    case 0:  src = aw1;              nch = 1024; ksh = 3; KC = 2; off = W1_OFF;        break;
    case 1:  src = aw2;              nch = 2048; ksh = 4; KC = 4; off = W2_OFF;        break;
    case 2:  src = awih;             nch = 2048; ksh = 4; KC = 4; off = WI_OFF;        break;
    case 3:  src = awih + 256 * HID; nch = 2048; ksh = 4; KC = 4; off = WG_OFF;        break;
    case 4:  src = awih + 384 * HID; nch = 2048; ksh = 4; KC = 4; off = WO_OFF;        break;
    case 5:  src = cw1;              nch = 1024; ksh = 3; KC = 2; off = PSTR + W1_OFF; break;
    case 6:  src = cw2;              nch = 2048; ksh = 4; KC = 4; off = PSTR + W2_OFF; break;
    case 7:  src = cwih;             nch = 2048; ksh = 4; KC = 4; off = PSTR + WI_OFF; break;
    case 8:  src = cwih + 256 * HID; nch = 2048; ksh = 4; KC = 4; off = PSTR + WG_OFF; break;
    default: src = cwih + 384 * HID; nch = 2048; ksh = 4; KC = 4; off = PSTR + WO_OFF; break;
  }
  if (idx >= nch) return;
  int row = idx >> ksh;
  int c16 = idx & ((1 << ksh) - 1);
  int b2 = row >> 4, r = row & 15, kc = c16 >> 2, ks = c16 & 3;
  const fx4* gp = (const fx4*)(src + (size_t)idx * 8);
  fx4 v0 = gp[0], v1 = gp[1];
  u32x4 u;
  u[0] = cvtpk(v0[0], v0[1]);
  u[1] = cvtpk(v0[2], v0[3]);
  u[2] = cvtpk(v1[0], v1[1]);
  u[3] = cvtpk(v1[2], v1[3]);
  int dst = (((b2 * KC + kc) * 4 + ks) * 16 + r) * 16;
  *(u32x4*)(ws + off + dst) = u;
}

// ---------------- main fused kernel ----------------------------------------
__global__ __launch_bounds__(256, 3) void fused_ac(
    const float* __restrict__ state, const float* __restrict__ ab1,
    const float* __restrict__ ab2, const float* __restrict__ cb1,
    const float* __restrict__ cb2, const float* __restrict__ mb,
    const float* __restrict__ lb, const float* __restrict__ vb,
    const char* __restrict__ ws, float* __restrict__ outp) {
  __shared__ __align__(16) unsigned short abuf[HID * HID];  // 32KB: X->H1->H2->h

  const int tid = threadIdx.x;
  const int lane = tid & 63;
  const int wv = tid >> 6;
  const int l15 = lane & 15;
  const int g4 = (lane >> 4) << 2;
  const int kb0 = (lane >> 4) << 4;
  const int woff = ((lane >> 4) << 8) + (l15 << 4);
  const int fb = wv << 5;  // feature band
  const int path = blockIdx.x >> 11;
  const int rbase = (blockIdx.x & 2047) << 7;

  const char* wsp = ws + (size_t)path * PSTR;
  const float* b1 = path ? cb1 : ab1;
  const float* b2 = path ? cb2 : ab2;
  const float* gbias = (const float*)(ws + GB_OFF + (size_t)path * 2048);
  const char* himg = ws + HEAD_OFF + (size_t)path * 4096;

  float* meanp = outp;
  float* stdp = outp + (size_t)NROWS * ACTD;
  float* valp = outp + (size_t)NROWS * ACTD * 2;

  // stage X [128][64] f32 -> bf16 swizzled (128B rows) into abuf
  {
    const float* xg = state + (size_t)rbase * 64;
    char* ab = (char*)abuf;
#pragma unroll
    for (int i = 0; i < 4; ++i) {
      int idx = tid + i * 256;
      int r = idx >> 3, c = idx & 7;
      const fx4* gp = (const fx4*)(xg + idx * 8);
      fx4 v0 = gp[0], v1 = gp[1];
      u32x4 u;
      u[0] = cvtpk(v0[0], v0[1]);
      u[1] = cvtpk(v0[2], v0[3]);
      u[2] = cvtpk(v1[0], v1[1]);
      u[3] = cvtpk(v1[2], v1[3]);
      *(u32x4*)(ab + r * 128 + ((c << 4) ^ ((r & 7) << 4))) = u;
    }
  }
  __syncthreads();

  fx4 acc[8][2];
  zacc(acc);
  gemm_f<2, 7>(wsp + W1_OFF, abuf, wv, lane, acc);  // H1 = X*W1^T
  __syncthreads();
  epi<true>(acc, b1, b1, abuf, fb, lane);
  __syncthreads();

  zacc(acc);
  gemm_f<4, 8>(wsp + W2_OFF, abuf, wv, lane, acc);  // H2 = H1*W2^T
  __syncthreads();
  epi<true>(acc, b2, b2, abuf, fb, lane);
  __syncthreads();

  // gate GEMMs: read-only on abuf -> no barriers between them
  fx4 bi0 = *(const fx4*)(gbias + fb + g4);
  fx4 bi1 = *(const fx4*)(gbias + fb + 16 + g4);
  fx4 bg0 = *(const fx4*)(gbias + 256 + fb + g4);
  fx4 bg1 = *(const fx4*)(gbias + 256 + fb + 16 + g4);
  fx4 bo0 = *(const fx4*)(gbias + 384 + fb + g4);
  fx4 bo1 = *(const fx4*)(gbias + 384 + fb + 16 + g4);

  zacc(acc);
  gemm_f<4, 8>(wsp + WI_OFF, abuf, wv, lane, acc);  // i gate
  fx4 gi[8][2];
#pragma unroll
  for (int jt = 0; jt < 8; ++jt)
#pragma unroll
    for (int it = 0; it < 2; ++it) {
      fx4 bv = it ? bi1 : bi0;
#pragma unroll
      for (int r = 0; r < 4; ++r) gi[jt][it][r] = fsig(acc[jt][it][r] + bv[r]);
    }

  zacc(acc);
  gemm_f<4, 8>(wsp + WG_OFF, abuf, wv, lane, acc);  // g gate
#pragma unroll
  for (int jt = 0; jt < 8; ++jt)
#pragma unroll
    for (int it = 0; it < 2; ++it) {
      fx4 bv = it ? bg1 : bg0;
#pragma unroll
      for (int r = 0; r < 4; ++r) {
        float c = gi[jt][it][r] * ftanh(acc[jt][it][r] + bv[r]);
        gi[jt][it][r] = ftanh(c);  // tanh(c)
      }
    }

  zacc(acc);
  gemm_f<4, 8>(wsp + WO_OFF, abuf, wv, lane, acc);  // o gate
#pragma unroll
  for (int jt = 0; jt < 8; ++jt)
#pragma unroll
    for (int it = 0; it < 2; ++it) {
      fx4 bv = it ? bo1 : bo0;
#pragma unroll
      for (int r = 0; r < 4; ++r)
        gi[jt][it][r] = fsig(acc[jt][it][r] + bv[r]) * gi[jt][it][r];  // h
    }
  __syncthreads();  // all gate reads of abuf done

  // h -> abuf (no relu, no bias)
  {
    char* ob = (char*)abuf;
#pragma unroll
    for (int it = 0; it < 2; ++it) {
      int n0 = fb + it * 16 + g4;
#pragma unroll
      for (int jt = 0; jt < 8; ++jt) {
        u32x2 u;
        u[0] = cvtpk(gi[jt][it][0], gi[jt][it][1]);
        u[1] = cvtpk(gi[jt][it][2], gi[jt][it][3]);
        int m = jt * 16 + l15;
        *(u32x2*)(ob + (m << 8) + ((n0 * 2) ^ ((m & 7) << 4))) = u;
      }
    }
  }
  __syncthreads();

  // head GEMM: row-split (wave handles its 32 rows), 16 head feats
  fx4 ha[2];
  ha[0] = fx4{0.f, 0.f, 0.f, 0.f};
  ha[1] = fx4{0.f, 0.f, 0.f, 0.f};
#pragma unroll
  for (int kc = 0; kc < 4; ++kc) {
    s16x8 w = *(const s16x8*)(himg + (kc << 10) + woff);
#pragma unroll
    for (int jt2 = 0; jt2 < 2; ++jt2) {
      s16x8 a = frag_ld(abuf, (wv << 5) + jt2 * 16 + l15, kc * 64 + kb0, 8);
      ha[jt2] = __builtin_amdgcn_mfma_f32_16x16x32_bf16(w, a, ha[jt2], 0, 0, 0);
    }
  }

  if (path == 0) {
    bool isMean = (g4 < 8);
    fx4 hb = isMean ? *(const fx4*)(mb + g4) : *(const fx4*)(lb + (g4 - 8));
#pragma unroll
    for (int jt2 = 0; jt2 < 2; ++jt2) {
      fx4 v = ha[jt2] + hb;
      int m = rbase + (wv << 5) + jt2 * 16 + l15;
      if (isMean) {
        *(fx4*)(meanp + (size_t)m * ACTD + g4) = v;
      } else {
#pragma unroll
        for (int r = 0; r < 4; ++r) v[r] = __expf(v[r]);
        *(fx4*)(stdp + (size_t)m * ACTD + (g4 - 8)) = v;
      }
    }
  } else if (g4 == 0) {
#pragma unroll
    for (int jt2 = 0; jt2 < 2; ++jt2) {
      int m = rbase + (wv << 5) + jt2 * 16 + l15;
      valp[m] = ha[jt2][0] + vb[0];
    }
  }
}

extern "C" void kernel_launch(void* const* d_in, const int* in_sizes, int n_in,
                              void* d_out, int out_size, void* d_ws,
                              size_t ws_size, hipStream_t stream) {
  (void)in_sizes; (void)n_in; (void)ws_size; (void)out_size;
  const float* state = (const float*)d_in[0];
  const float* aw1 = (const float*)d_in[1];
  const float* ab1 = (const float*)d_in[2];
  const float* aw2 = (const float*)d_in[3];
  const float* ab2 = (const float*)d_in[4];
  const float* cw1 = (const float*)d_in[5];
  const float* cb1 = (const float*)d_in[6];
  const float* cw2 = (const float*)d_in[7];
  const float* cb2 = (const float*)d_in[8];
  const float* awih = (const float*)d_in[9];
  const float* abih = (const float*)d_in[11];
  const float* abhh = (const float*)d_in[12];
  const float* cwih = (const float*)d_in[13];
  const float* cbih = (const float*)d_in[15];
  const float* cbhh = (const float*)d_in[16];
  const float* mw = (const float*)d_in[17];
  const float* mb = (const float*)d_in[18];
  const float* lw = (const float*)d_in[19];
  const float* lb = (const float*)d_in[20];
  const float* vw = (const float*)d_in[21];
  const float* vb = (const float*)d_in[22];
  char* ws = (char*)d_ws;

  prep_weights<<<dim3(8, 14), 256, 0, stream>>>(
      aw1, aw2, awih, cw1, cw2, cwih, mw, lw, vw, abih, abhh, cbih, cbhh, ws);
  fused_ac<<<4096, 256, 0, stream>>>(state, ab1, ab2, cb1, cb2, mb, lb, vb, ws,
                                     (float*)d_out);
}

// Round 4
// 225.589 us; speedup vs baseline: 2.4944x; 2.4944x over previous
//
#include <hip/hip_runtime.h>

// Fused actor-critic forward for S=256,B=1024,D=64,H=128,A=8.
// R4 = R2 structure with the spill fixed: launch_bounds(256,2) (R3's (256,3)
// caused 1.5GB of scratch spill traffic), gate biases loaded just-in-time.
// Weights: bf16 fragment-ordered images in ws (prep kernel), global->VGPR.
// Single 32KB LDS activation buffer (X -> H1 -> H2 -> h). cvt_pk bf16 packs.

#define NROWS (256 * 1024)
#define HID 128
#define ACTD 8

// ws layout (bytes)
#define W1_OFF 0                  // [128][64]  frag-img 16KB
#define W2_OFF 16384              // [128][128] frag-img 32KB
#define WI_OFF 49152              // wih rows 0..127   32KB
#define WG_OFF 81920              // wih rows 256..383 32KB
#define WO_OFF 114688             // wih rows 384..511 32KB
#define PSTR 147456               // per-path stride
#define HEAD_OFF (2 * PSTR)       // actor [mw;lw] 4KB, critic [vw;0] 4KB
#define GB_OFF (HEAD_OFF + 8192)  // combined bih+bhh, 512 f32 per path

typedef __attribute__((ext_vector_type(8))) short s16x8;
typedef __attribute__((ext_vector_type(4))) float fx4;
typedef __attribute__((ext_vector_type(2))) unsigned int u32x2;
typedef __attribute__((ext_vector_type(4))) unsigned int u32x4;

__device__ __forceinline__ unsigned int cvtpk(float lo, float hi) {
  unsigned int r;
  asm("v_cvt_pk_bf16_f32 %0, %1, %2" : "=v"(r) : "v"(lo), "v"(hi));
  return r;
}

__device__ __forceinline__ float fsig(float x) {
  return __builtin_amdgcn_rcpf(1.0f + __expf(-x));
}
__device__ __forceinline__ float ftanh(float x) {
  return 2.0f * __builtin_amdgcn_rcpf(1.0f + __expf(-2.0f * x)) - 1.0f;
}

// 8 bf16 from swizzled LDS act tile: row-major, 2^rowsh bytes/row,
// chunk XOR (row&7)<<4.
__device__ __forceinline__ s16x8 frag_ld(const unsigned short* base, int row,
                                         int kbyte, int rowsh) {
  int byte = (row << rowsh) + (kbyte ^ ((row & 7) << 4));
  return *(const s16x8*)((const char*)base + byte);
}

__device__ __forceinline__ void zacc(fx4 acc[8][2]) {
#pragma unroll
  for (int j = 0; j < 8; ++j)
#pragma unroll
    for (int i = 0; i < 2; ++i) acc[j][i] = fx4{0.f, 0.f, 0.f, 0.f};
}

// Feature-split GEMM: wave wv computes feats wv*32..+31 for all 128 rows.
// Weights from frag-ordered global image: 1KB block per (featTile16, kc),
// laid out [ks:4][r:16][16B] so a wave load is one contiguous burst.
template <int KC, int ASH>
__device__ __forceinline__ void gemm_f(const char* wimg,
                                       const unsigned short* at, int wv,
                                       int lane, fx4 acc[8][2]) {
  const int l15 = lane & 15;
  const int kb0 = (lane >> 4) << 4;
  const int woff = ((lane >> 4) << 8) + (l15 << 4);
#pragma unroll
  for (int kc = 0; kc < KC; ++kc) {
    s16x8 w0 = *(const s16x8*)(wimg + (((wv * 2 + 0) * KC + kc) << 10) + woff);
    s16x8 w1 = *(const s16x8*)(wimg + (((wv * 2 + 1) * KC + kc) << 10) + woff);
#pragma unroll
    for (int jt = 0; jt < 8; ++jt) {
      s16x8 a = frag_ld(at, jt * 16 + l15, kc * 64 + kb0, ASH);
      acc[jt][0] = __builtin_amdgcn_mfma_f32_16x16x32_bf16(w0, a, acc[jt][0], 0, 0, 0);
      acc[jt][1] = __builtin_amdgcn_mfma_f32_16x16x32_bf16(w1, a, acc[jt][1], 0, 0, 0);
    }
  }
}

// acc + bias -> (relu) -> bf16 -> swizzled abuf [row][feat] 256B rows
template <bool RELU>
__device__ __forceinline__ void epi(fx4 acc[8][2], const float* __restrict__ b0,
                                    unsigned short* obuf, int fb, int lane) {
  const int g4 = (lane >> 4) << 2;
  const int l15 = lane & 15;
  char* ob = (char*)obuf;
#pragma unroll
  for (int it = 0; it < 2; ++it) {
    int n0 = fb + it * 16 + g4;
    fx4 bv = *(const fx4*)(b0 + n0);
#pragma unroll
    for (int jt = 0; jt < 8; ++jt) {
      fx4 v = acc[jt][it] + bv;
      if (RELU) {
#pragma unroll
        for (int r = 0; r < 4; ++r) v[r] = fmaxf(v[r], 0.0f);
      }
      u32x2 u;
      u[0] = cvtpk(v[0], v[1]);
      u[1] = cvtpk(v[2], v[3]);
      int m = jt * 16 + l15;
      *(u32x2*)(ob + (m << 8) + ((n0 * 2) ^ ((m & 7) << 4))) = u;
    }
  }
}

// ---------------- prep: weights -> bf16 fragment-ordered images ------------
__global__ void prep_weights(const float* __restrict__ aw1,
                             const float* __restrict__ aw2,
                             const float* __restrict__ awih,
                             const float* __restrict__ cw1,
                             const float* __restrict__ cw2,
                             const float* __restrict__ cwih,
                             const float* __restrict__ mw,
                             const float* __restrict__ lw,
                             const float* __restrict__ vw,
                             const float* __restrict__ abih,
                             const float* __restrict__ abhh,
                             const float* __restrict__ cbih,
                             const float* __restrict__ cbhh,
                             char* __restrict__ ws) {
  int y = blockIdx.y;
  int idx = blockIdx.x * 256 + threadIdx.x;
  if (y >= 12) {  // combined gate biases (f32)
    if (idx < 512) {
      float* dst = (float*)(ws + GB_OFF + (size_t)(y - 12) * 2048);
      const float* b0 = (y == 12) ? abih : cbih;
      const float* b1 = (y == 12) ? abhh : cbhh;
      dst[idx] = b0[idx] + b1[idx];
    }
    return;
  }
  if (y >= 10) {  // head images: 16 rows x 128 cols
    if (idx >= 256) return;
    int row = idx >> 4, c16 = idx & 15, kc = c16 >> 2, ks = c16 & 3;
    fx4 v0 = {0.f, 0.f, 0.f, 0.f}, v1 = v0;
    if (y == 10) {
      const float* src = (row < 8) ? (mw + (size_t)row * HID + c16 * 8)
                                   : (lw + (size_t)(row - 8) * HID + c16 * 8);
      v0 = ((const fx4*)src)[0];
      v1 = ((const fx4*)src)[1];
    } else if (row == 0) {
      const float* src = vw + c16 * 8;
      v0 = ((const fx4*)src)[0];
      v1 = ((const fx4*)src)[1];
    }
    u32x4 u;
    u[0] = cvtpk(v0[0], v0[1]);
    u[1] = cvtpk(v0[2], v0[3]);
    u[2] = cvtpk(v1[0], v1[1]);
    u[3] = cvtpk(v1[2], v1[3]);
    int dst = ((kc * 4 + ks) * 16 + row) * 16;
    *(u32x4*)(ws + HEAD_OFF + (size_t)(y - 10) * 4096 + dst) = u;
    return;
  }
  const float* src;
  int nch, ksh, KC, off;
  switch (y) {
    case 0:  src = aw1;              nch = 1024; ksh = 3; KC = 2; off = W1_OFF;        break;
    case 1:  src = aw2;              nch = 2048; ksh = 4; KC = 4; off = W2_OFF;        break;
    case 2:  src = awih;             nch = 2048; ksh = 4; KC = 4; off = WI_OFF;        break;
    case 3:  src = awih + 256 * HID; nch = 2048; ksh = 4; KC = 4; off = WG_OFF;        break;
    case 4:  src = awih + 384 * HID; nch = 2048; ksh = 4; KC = 4; off = WO_OFF;        break;
    case 5:  src = cw1;              nch = 1024; ksh = 3; KC = 2; off = PSTR + W1_OFF; break;
    case 6:  src = cw2;              nch = 2048; ksh = 4; KC = 4; off = PSTR + W2_OFF; break;
    case 7:  src = cwih;             nch = 2048; ksh = 4; KC = 4; off = PSTR + WI_OFF; break;
    case 8:  src = cwih + 256 * HID; nch = 2048; ksh = 4; KC = 4; off = PSTR + WG_OFF; break;
    default: src = cwih + 384 * HID; nch = 2048; ksh = 4; KC = 4; off = PSTR + WO_OFF; break;
  }
  if (idx >= nch) return;
  int row = idx >> ksh;
  int c16 = idx & ((1 << ksh) - 1);
  int b2 = row >> 4, r = row & 15, kc = c16 >> 2, ks = c16 & 3;
  const fx4* gp = (const fx4*)(src + (size_t)idx * 8);
  fx4 v0 = gp[0], v1 = gp[1];
  u32x4 u;
  u[0] = cvtpk(v0[0], v0[1]);
  u[1] = cvtpk(v0[2], v0[3]);
  u[2] = cvtpk(v1[0], v1[1]);
  u[3] = cvtpk(v1[2], v1[3]);
  int dst = (((b2 * KC + kc) * 4 + ks) * 16 + r) * 16;
  *(u32x4*)(ws + off + dst) = u;
}

// ---------------- main fused kernel ----------------------------------------
__global__ __launch_bounds__(256, 2) void fused_ac(
    const float* __restrict__ state, const float* __restrict__ ab1,
    const float* __restrict__ ab2, const float* __restrict__ cb1,
    const float* __restrict__ cb2, const float* __restrict__ mb,
    const float* __restrict__ lb, const float* __restrict__ vb,
    const char* __restrict__ ws, float* __restrict__ outp) {
  __shared__ __align__(16) unsigned short abuf[HID * HID];  // 32KB: X->H1->H2->h

  const int tid = threadIdx.x;
  const int lane = tid & 63;
  const int wv = tid >> 6;
  const int l15 = lane & 15;
  const int g4 = (lane >> 4) << 2;
  const int kb0 = (lane >> 4) << 4;
  const int woff = ((lane >> 4) << 8) + (l15 << 4);
  const int fb = wv << 5;  // feature band
  const int path = blockIdx.x >> 11;
  const int rbase = (blockIdx.x & 2047) << 7;

  const char* wsp = ws + (size_t)path * PSTR;
  const float* b1 = path ? cb1 : ab1;
  const float* b2 = path ? cb2 : ab2;
  const float* gbias = (const float*)(ws + GB_OFF + (size_t)path * 2048);
  const char* himg = ws + HEAD_OFF + (size_t)path * 4096;

  float* meanp = outp;
  float* stdp = outp + (size_t)NROWS * ACTD;
  float* valp = outp + (size_t)NROWS * ACTD * 2;

  // stage X [128][64] f32 -> bf16 swizzled (128B rows) into abuf
  {
    const float* xg = state + (size_t)rbase * 64;
    char* ab = (char*)abuf;
#pragma unroll
    for (int i = 0; i < 4; ++i) {
      int idx = tid + i * 256;
      int r = idx >> 3, c = idx & 7;
      const fx4* gp = (const fx4*)(xg + idx * 8);
      fx4 v0 = gp[0], v1 = gp[1];
      u32x4 u;
      u[0] = cvtpk(v0[0], v0[1]);
      u[1] = cvtpk(v0[2], v0[3]);
      u[2] = cvtpk(v1[0], v1[1]);
      u[3] = cvtpk(v1[2], v1[3]);
      *(u32x4*)(ab + r * 128 + ((c << 4) ^ ((r & 7) << 4))) = u;
    }
  }
  __syncthreads();

  fx4 acc[8][2];
  zacc(acc);
  gemm_f<2, 7>(wsp + W1_OFF, abuf, wv, lane, acc);  // H1 = X*W1^T
  __syncthreads();
  epi<true>(acc, b1, abuf, fb, lane);
  __syncthreads();

  zacc(acc);
  gemm_f<4, 8>(wsp + W2_OFF, abuf, wv, lane, acc);  // H2 = H1*W2^T
  __syncthreads();
  epi<true>(acc, b2, abuf, fb, lane);
  __syncthreads();

  // gate GEMMs: read-only on abuf -> no barriers between them.
  // Biases loaded just-in-time to keep live-register peak low.
  zacc(acc);
  gemm_f<4, 8>(wsp + WI_OFF, abuf, wv, lane, acc);  // i gate
  fx4 gi[8][2];
#pragma unroll
  for (int it = 0; it < 2; ++it) {
    fx4 bv = *(const fx4*)(gbias + fb + it * 16 + g4);
#pragma unroll
    for (int jt = 0; jt < 8; ++jt)
#pragma unroll
      for (int r = 0; r < 4; ++r) gi[jt][it][r] = fsig(acc[jt][it][r] + bv[r]);
  }

  zacc(acc);
  gemm_f<4, 8>(wsp + WG_OFF, abuf, wv, lane, acc);  // g gate
#pragma unroll
  for (int it = 0; it < 2; ++it) {
    fx4 bv = *(const fx4*)(gbias + 256 + fb + it * 16 + g4);
#pragma unroll
    for (int jt = 0; jt < 8; ++jt)
#pragma unroll
      for (int r = 0; r < 4; ++r) {
        float c = gi[jt][it][r] * ftanh(acc[jt][it][r] + bv[r]);
        gi[jt][it][r] = ftanh(c);  // tanh(c)
      }
  }

  zacc(acc);
  gemm_f<4, 8>(wsp + WO_OFF, abuf, wv, lane, acc);  // o gate
#pragma unroll
  for (int it = 0; it < 2; ++it) {
    fx4 bv = *(const fx4*)(gbias + 384 + fb + it * 16 + g4);
#pragma unroll
    for (int jt = 0; jt < 8; ++jt)
#pragma unroll
      for (int r = 0; r < 4; ++r)
        gi[jt][it][r] = fsig(acc[jt][it][r] + bv[r]) * gi[jt][it][r];  // h
  }
  __syncthreads();  // all gate reads of abuf done

  // h -> abuf (no relu, no bias)
  {
    char* ob = (char*)abuf;
#pragma unroll
    for (int it = 0; it < 2; ++it) {
      int n0 = fb + it * 16 + g4;
#pragma unroll
      for (int jt = 0; jt < 8; ++jt) {
        u32x2 u;
        u[0] = cvtpk(gi[jt][it][0], gi[jt][it][1]);
        u[1] = cvtpk(gi[jt][it][2], gi[jt][it][3]);
        int m = jt * 16 + l15;
        *(u32x2*)(ob + (m << 8) + ((n0 * 2) ^ ((m & 7) << 4))) = u;
      }
    }
  }
  __syncthreads();

  // head GEMM: row-split (wave handles its 32 rows), 16 head feats
  fx4 ha[2];
  ha[0] = fx4{0.f, 0.f, 0.f, 0.f};
  ha[1] = fx4{0.f, 0.f, 0.f, 0.f};
#pragma unroll
  for (int kc = 0; kc < 4; ++kc) {
    s16x8 w = *(const s16x8*)(himg + (kc << 10) + woff);
#pragma unroll
    for (int jt2 = 0; jt2 < 2; ++jt2) {
      s16x8 a = frag_ld(abuf, (wv << 5) + jt2 * 16 + l15, kc * 64 + kb0, 8);
      ha[jt2] = __builtin_amdgcn_mfma_f32_16x16x32_bf16(w, a, ha[jt2], 0, 0, 0);
    }
  }

  if (path == 0) {
    bool isMean = (g4 < 8);
    fx4 hb = isMean ? *(const fx4*)(mb + g4) : *(const fx4*)(lb + (g4 - 8));
#pragma unroll
    for (int jt2 = 0; jt2 < 2; ++jt2) {
      fx4 v = ha[jt2] + hb;
      int m = rbase + (wv << 5) + jt2 * 16 + l15;
      if (isMean) {
        *(fx4*)(meanp + (size_t)m * ACTD + g4) = v;
      } else {
#pragma unroll
        for (int r = 0; r < 4; ++r) v[r] = __expf(v[r]);
        *(fx4*)(stdp + (size_t)m * ACTD + (g4 - 8)) = v;
      }
    }
  } else if (g4 == 0) {
#pragma unroll
    for (int jt2 = 0; jt2 < 2; ++jt2) {
      int m = rbase + (wv << 5) + jt2 * 16 + l15;
      valp[m] = ha[jt2][0] + vb[0];
    }
  }
}

extern "C" void kernel_launch(void* const* d_in, const int* in_sizes, int n_in,
                              void* d_out, int out_size, void* d_ws,
                              size_t ws_size, hipStream_t stream) {
  (void)in_sizes; (void)n_in; (void)ws_size; (void)out_size;
  const float* state = (const float*)d_in[0];
  const float* aw1 = (const float*)d_in[1];
  const float* ab1 = (const float*)d_in[2];
  const float* aw2 = (const float*)d_in[3];
  const float* ab2 = (const float*)d_in[4];
  const float* cw1 = (const float*)d_in[5];
  const float* cb1 = (const float*)d_in[6];
  const float* cw2 = (const float*)d_in[7];
  const float* cb2 = (const float*)d_in[8];
  const float* awih = (const float*)d_in[9];
  const float* abih = (const float*)d_in[11];
  const float* abhh = (const float*)d_in[12];
  const float* cwih = (const float*)d_in[13];
  const float* cbih = (const float*)d_in[15];
  const float* cbhh = (const float*)d_in[16];
  const float* mw = (const float*)d_in[17];
  const float* mb = (const float*)d_in[18];
  const float* lw = (const float*)d_in[19];
  const float* lb = (const float*)d_in[20];
  const float* vw = (const float*)d_in[21];
  const float* vb = (const float*)d_in[22];
  char* ws = (char*)d_ws;

  prep_weights<<<dim3(8, 14), 256, 0, stream>>>(
      aw1, aw2, awih, cw1, cw2, cwih, mw, lw, vw, abih, abhh, cbih, cbhh, ws);
  fused_ac<<<4096, 256, 0, stream>>>(state, ab1, ab2, cb1, cb2, mb, lb, vb, ws,
                                     (float*)d_out);
}

// Round 5
// 128.588 us; speedup vs baseline: 4.3761x; 1.7544x over previous
//
#include <hip/hip_runtime.h>

// Fused actor-critic forward for S=256,B=1024,D=64,H=128,A=8.
// R5: R1's LDS-weight structure, resized for occupancy: 64-row blocks,
// feature-split waves (acc[4][2]=32 regs), LDS = 32KB wbuf + 16KB abuf =
// 48KB -> 3 blocks/CU at launch_bounds(256,3). Gate math reduced to
// 6 transcendentals/element via combined-denominator sigmoid/tanh algebra
// with bias pre-scaled into exp2 form by the prep kernel.

#define NROWS (256 * 1024)
#define HID 128
#define ACTD 8

// ws layout (bytes)
#define W1_OFF 0                  // [128 feat][64 K]  swizzled img 16KB
#define W2_OFF 16384              // [128][128] 32KB
#define WI_OFF 49152              // wih rows 0..127   32KB
#define WG_OFF 81920              // wih rows 256..383 32KB
#define WO_OFF 114688             // wih rows 384..511 32KB
#define PSTR 147456               // per-path stride
#define HEAD_OFF (2 * PSTR)       // actor [mw;lw] 4KB, critic [vw;0] 4KB
#define GB_OFF (HEAD_OFF + 8192)  // prescaled gate biases, 384 f32 per path

#define NEG_L (-1.4426950408889634f)
#define TWO_L (2.8853900817779268f)

typedef __attribute__((ext_vector_type(8))) short s16x8;
typedef __attribute__((ext_vector_type(4))) float fx4;
typedef __attribute__((ext_vector_type(2))) unsigned int u32x2;
typedef __attribute__((ext_vector_type(4))) unsigned int u32x4;

__device__ __forceinline__ unsigned int cvtpk(float lo, float hi) {
  unsigned int r;
  asm("v_cvt_pk_bf16_f32 %0, %1, %2" : "=v"(r) : "v"(lo), "v"(hi));
  return r;
}

__device__ __forceinline__ float ex2(float x) {
  return __builtin_amdgcn_exp2f(x);
}
__device__ __forceinline__ float frcp(float x) {
  return __builtin_amdgcn_rcpf(x);
}

// async 16B global->LDS DMA (linear dest; source is pre-swizzled image)
__device__ __forceinline__ void dma16(const void* g, void* l) {
  __builtin_amdgcn_global_load_lds(
      (__attribute__((address_space(1))) void*)(g),
      (__attribute__((address_space(3))) void*)(l), 16, 0, 0);
}

// 8 bf16 from swizzled LDS tile: row-major 2^rowsh B/row, chunk XOR (row&7)<<4
__device__ __forceinline__ s16x8 frag_ld(const unsigned short* base, int row,
                                         int kbyte, int rowsh) {
  int byte = (row << rowsh) + (kbyte ^ ((row & 7) << 4));
  return *(const s16x8*)((const char*)base + byte);
}

__device__ __forceinline__ void zacc(fx4 acc[4][2]) {
#pragma unroll
  for (int j = 0; j < 4; ++j)
#pragma unroll
    for (int i = 0; i < 2; ++i) acc[j][i] = fx4{0.f, 0.f, 0.f, 0.f};
}

// Feature-split GEMM: wave wv -> feats wv*32..+31, all 64 rows.
// D[i=feat][j=row]; lane holds feats (wv*32+it*16+g4..+3) of row jt*16+(l&15).
template <int KC, int WSH, int ASH>
__device__ __forceinline__ void gemm_fs(const unsigned short* wt,
                                        const unsigned short* at, int wv,
                                        int lane, fx4 acc[4][2]) {
  const int l15 = lane & 15;
  const int kb0 = (lane >> 4) << 4;
#pragma unroll
  for (int kc = 0; kc < KC; ++kc) {
    int kbyte = kc * 64 + kb0;
    s16x8 w0 = frag_ld(wt, (wv * 2 + 0) * 16 + l15, kbyte, WSH);
    s16x8 w1 = frag_ld(wt, (wv * 2 + 1) * 16 + l15, kbyte, WSH);
#pragma unroll
    for (int jt = 0; jt < 4; ++jt) {
      s16x8 a = frag_ld(at, jt * 16 + l15, kbyte, ASH);
      acc[jt][0] = __builtin_amdgcn_mfma_f32_16x16x32_bf16(w0, a, acc[jt][0], 0, 0, 0);
      acc[jt][1] = __builtin_amdgcn_mfma_f32_16x16x32_bf16(w1, a, acc[jt][1], 0, 0, 0);
    }
  }
}

// acc + bias -> relu -> bf16 -> swizzled abuf [64 rows][128 feats] 256B rows
__device__ __forceinline__ void epi_relu(fx4 acc[4][2],
                                         const float* __restrict__ bias,
                                         unsigned short* obuf, int fb,
                                         int lane) {
  const int g4 = (lane >> 4) << 2;
  const int l15 = lane & 15;
  char* ob = (char*)obuf;
#pragma unroll
  for (int it = 0; it < 2; ++it) {
    int n0 = fb + it * 16 + g4;
    fx4 bv = *(const fx4*)(bias + n0);
#pragma unroll
    for (int jt = 0; jt < 4; ++jt) {
      fx4 v = acc[jt][it] + bv;
#pragma unroll
      for (int r = 0; r < 4; ++r) v[r] = fmaxf(v[r], 0.0f);
      u32x2 u;
      u[0] = cvtpk(v[0], v[1]);
      u[1] = cvtpk(v[2], v[3]);
      int m = jt * 16 + l15;
      *(u32x2*)(ob + (m << 8) + ((n0 * 2) ^ ((m & 7) << 4))) = u;
    }
  }
}

// ---------------- prep: weights -> bf16 swizzled LDS images ----------------
__global__ void prep_weights(const float* __restrict__ aw1,
                             const float* __restrict__ aw2,
                             const float* __restrict__ awih,
                             const float* __restrict__ cw1,
                             const float* __restrict__ cw2,
                             const float* __restrict__ cwih,
                             const float* __restrict__ mw,
                             const float* __restrict__ lw,
                             const float* __restrict__ vw,
                             const float* __restrict__ abih,
                             const float* __restrict__ abhh,
                             const float* __restrict__ cbih,
                             const float* __restrict__ cbhh,
                             char* __restrict__ ws) {
  int y = blockIdx.y;
  int idx = blockIdx.x * 256 + threadIdx.x;
  if (y >= 12) {  // prescaled gate biases: [pgi(128); pgg(128); pgo(128)]
    if (idx < 384) {
      float* dst = (float*)(ws + GB_OFF + (size_t)(y - 12) * 1536);
      const float* b0 = (y == 12) ? abih : cbih;
      const float* b1 = (y == 12) ? abhh : cbhh;
      int sect = idx >> 7, f = idx & 127;
      int srow = (sect == 0) ? f : (sect == 1) ? 256 + f : 384 + f;
      float scale = (sect == 1) ? TWO_L : NEG_L;
      dst[idx] = scale * (b0[srow] + b1[srow]);
    }
    return;
  }
  if (y >= 10) {  // head images: [16 rows][128 K] swizzled, 4KB
    if (idx >= 256) return;
    int row = idx >> 4, c16 = idx & 15;
    fx4 v0 = {0.f, 0.f, 0.f, 0.f}, v1 = v0;
    if (y == 10) {
      const float* src = (row < 8) ? (mw + (size_t)row * HID + c16 * 8)
                                   : (lw + (size_t)(row - 8) * HID + c16 * 8);
      v0 = ((const fx4*)src)[0];
      v1 = ((const fx4*)src)[1];
    } else if (row == 0) {
      const float* src = vw + c16 * 8;
      v0 = ((const fx4*)src)[0];
      v1 = ((const fx4*)src)[1];
    }
    u32x4 u;
    u[0] = cvtpk(v0[0], v0[1]);
    u[1] = cvtpk(v0[2], v0[3]);
    u[2] = cvtpk(v1[0], v1[1]);
    u[3] = cvtpk(v1[2], v1[3]);
    int byte = (row << 8) + ((c16 << 4) ^ ((row & 7) << 4));
    *(u32x4*)(ws + HEAD_OFF + (size_t)(y - 10) * 4096 + byte) = u;
    return;
  }
  const float* src;
  int nch, sh, off;
  switch (y) {
    case 0:  src = aw1;              nch = 1024; sh = 3; off = W1_OFF;        break;
    case 1:  src = aw2;              nch = 2048; sh = 4; off = W2_OFF;        break;
    case 2:  src = awih;             nch = 2048; sh = 4; off = WI_OFF;        break;
    case 3:  src = awih + 256 * HID; nch = 2048; sh = 4; off = WG_OFF;        break;
    case 4:  src = awih + 384 * HID; nch = 2048; sh = 4; off = WO_OFF;        break;
    case 5:  src = cw1;              nch = 1024; sh = 3; off = PSTR + W1_OFF; break;
    case 6:  src = cw2;              nch = 2048; sh = 4; off = PSTR + W2_OFF; break;
    case 7:  src = cwih;             nch = 2048; sh = 4; off = PSTR + WI_OFF; break;
    case 8:  src = cwih + 256 * HID; nch = 2048; sh = 4; off = PSTR + WG_OFF; break;
    default: src = cwih + 384 * HID; nch = 2048; sh = 4; off = PSTR + WO_OFF; break;
  }
  if (idx >= nch) return;
  int r = idx >> sh;
  int c = idx & ((1 << sh) - 1);
  const fx4* gp = (const fx4*)(src + (size_t)idx * 8);
  fx4 v0 = gp[0], v1 = gp[1];
  u32x4 u;
  u[0] = cvtpk(v0[0], v0[1]);
  u[1] = cvtpk(v0[2], v0[3]);
  u[2] = cvtpk(v1[0], v1[1]);
  u[3] = cvtpk(v1[2], v1[3]);
  int byte = (r << (sh + 4)) + ((c << 4) ^ ((r & 7) << 4));
  *(u32x4*)(ws + off + byte) = u;
}

// ---------------- main fused kernel: one path x 64 rows per block ----------
__global__ __launch_bounds__(256, 3) void fused_ac(
    const float* __restrict__ state, const float* __restrict__ ab1,
    const float* __restrict__ ab2, const float* __restrict__ cb1,
    const float* __restrict__ cb2, const float* __restrict__ mb,
    const float* __restrict__ lb, const float* __restrict__ vb,
    const char* __restrict__ ws, float* __restrict__ outp) {
  __shared__ __align__(16) unsigned short wbuf[16384];  // 32KB weights (+X)
  __shared__ __align__(16) unsigned short abuf[8192];   // 16KB acts

  const int tid = threadIdx.x;
  const int lane = tid & 63;
  const int wv = tid >> 6;
  const int l15 = lane & 15;
  const int g4 = (lane >> 4) << 2;
  const int kb0 = (lane >> 4) << 4;
  const int fb = wv << 5;  // feature band base
  const int path = blockIdx.x >> 12;
  const int rbase = (blockIdx.x & 4095) << 6;  // 64 rows per block

  const char* wsp = ws + (size_t)path * PSTR;
  const float* b1 = path ? cb1 : ab1;
  const float* b2 = path ? cb2 : ab2;
  const float* gb = (const float*)(ws + GB_OFF + (size_t)path * 1536);
  char* wb = (char*)wbuf;

  float* meanp = outp;
  float* stdp = outp + (size_t)NROWS * ACTD;
  float* valp = outp + (size_t)NROWS * ACTD * 2;

  // DMA W1 image (16KB) ; stage X [64][64] f32->bf16 swizzled at wbuf+16KB
#pragma unroll
  for (int i = 0; i < 4; ++i) dma16(wsp + W1_OFF + (tid + i * 256) * 16, wb + (tid + i * 256) * 16);
  {
    const float* xg = state + (size_t)rbase * 64;
#pragma unroll
    for (int i = 0; i < 2; ++i) {
      int idx = tid + i * 256;
      int r = idx >> 3, c = idx & 7;
      const fx4* gp = (const fx4*)(xg + idx * 8);
      fx4 v0 = gp[0], v1 = gp[1];
      u32x4 u;
      u[0] = cvtpk(v0[0], v0[1]);
      u[1] = cvtpk(v0[2], v0[3]);
      u[2] = cvtpk(v1[0], v1[1]);
      u[3] = cvtpk(v1[2], v1[3]);
      *(u32x4*)(wb + 16384 + r * 128 + ((c << 4) ^ ((r & 7) << 4))) = u;
    }
  }
  __syncthreads();

  fx4 acc[4][2];
  zacc(acc);
  gemm_fs<2, 7, 7>(wbuf, wbuf + 8192, wv, lane, acc);  // H1 = X*W1^T
  __syncthreads();
#pragma unroll
  for (int i = 0; i < 8; ++i) dma16(wsp + W2_OFF + (tid + i * 256) * 16, wb + (tid + i * 256) * 16);
  epi_relu(acc, b1, abuf, fb, lane);
  __syncthreads();

  zacc(acc);
  gemm_fs<4, 8, 8>(wbuf, abuf, wv, lane, acc);  // H2 = H1*W2^T
  __syncthreads();
#pragma unroll
  for (int i = 0; i < 8; ++i) dma16(wsp + WI_OFF + (tid + i * 256) * 16, wb + (tid + i * 256) * 16);
  epi_relu(acc, b2, abuf, fb, lane);
  __syncthreads();

  zacc(acc);
  gemm_fs<4, 8, 8>(wbuf, abuf, wv, lane, acc);  // i gate
  __syncthreads();
#pragma unroll
  for (int i = 0; i < 8; ++i) dma16(wsp + WG_OFF + (tid + i * 256) * 16, wb + (tid + i * 256) * 16);
  fx4 carry[4][2];  // Ei -> Ec -> (used for h)
#pragma unroll
  for (int it = 0; it < 2; ++it) {
    fx4 pv = *(const fx4*)(gb + fb + it * 16 + g4);
#pragma unroll
    for (int jt = 0; jt < 4; ++jt)
#pragma unroll
      for (int r = 0; r < 4; ++r)
        carry[jt][it][r] = ex2(fmaf(acc[jt][it][r], NEG_L, pv[r]));  // e^{-i}
  }
  __syncthreads();

  zacc(acc);
  gemm_fs<4, 8, 8>(wbuf, abuf, wv, lane, acc);  // g gate
  __syncthreads();
#pragma unroll
  for (int i = 0; i < 8; ++i) dma16(wsp + WO_OFF + (tid + i * 256) * 16, wb + (tid + i * 256) * 16);
#pragma unroll
  for (int it = 0; it < 2; ++it) {
    fx4 pv = *(const fx4*)(gb + 128 + fb + it * 16 + g4);
#pragma unroll
    for (int jt = 0; jt < 4; ++jt)
#pragma unroll
      for (int r = 0; r < 4; ++r) {
        float Eg = ex2(fmaf(acc[jt][it][r], TWO_L, pv[r]));  // e^{2g}
        float c = (Eg - 1.0f) * frcp((Eg + 1.0f) * (carry[jt][it][r] + 1.0f));
        carry[jt][it][r] = ex2(c * TWO_L);  // e^{2c}
      }
  }
  __syncthreads();

  zacc(acc);
  gemm_fs<4, 8, 8>(wbuf, abuf, wv, lane, acc);  // o gate
  __syncthreads();  // all gate reads of wbuf+abuf done
  if (tid < 256) dma16(ws + HEAD_OFF + (size_t)path * 4096 + tid * 16, wb + tid * 16);
  {
    char* ob = (char*)abuf;
#pragma unroll
    for (int it = 0; it < 2; ++it) {
      fx4 pv = *(const fx4*)(gb + 256 + fb + it * 16 + g4);
      int n0 = fb + it * 16 + g4;
#pragma unroll
      for (int jt = 0; jt < 4; ++jt) {
        fx4 h;
#pragma unroll
        for (int r = 0; r < 4; ++r) {
          float Eo = ex2(fmaf(acc[jt][it][r], NEG_L, pv[r]));  // e^{-o}
          float Ec = carry[jt][it][r];
          h[r] = (Ec - 1.0f) * frcp((Ec + 1.0f) * (Eo + 1.0f));
        }
        u32x2 u;
        u[0] = cvtpk(h[0], h[1]);
        u[1] = cvtpk(h[2], h[3]);
        int m = jt * 16 + l15;
        *(u32x2*)(ob + (m << 8) + ((n0 * 2) ^ ((m & 7) << 4))) = u;
      }
    }
  }
  __syncthreads();

  // head GEMM: wave wv -> rows wv*16..+15; head tile [16][128] in wbuf
  fx4 ha = fx4{0.f, 0.f, 0.f, 0.f};
#pragma unroll
  for (int kc = 0; kc < 4; ++kc) {
    int kbyte = kc * 64 + kb0;
    s16x8 w = frag_ld(wbuf, l15, kbyte, 8);
    s16x8 a = frag_ld(abuf, (wv << 4) + l15, kbyte, 8);
    ha = __builtin_amdgcn_mfma_f32_16x16x32_bf16(w, a, ha, 0, 0, 0);
  }

  int m = rbase + (wv << 4) + l15;
  if (path == 0) {
    if (g4 < 8) {
      fx4 v = ha + *(const fx4*)(mb + g4);
      *(fx4*)(meanp + (size_t)m * ACTD + g4) = v;
    } else {
      fx4 v;
#pragma unroll
      for (int r = 0; r < 4; ++r) v[r] = __expf(ha[r] + lb[g4 - 8 + r]);
      *(fx4*)(stdp + (size_t)m * ACTD + (g4 - 8)) = v;
    }
  } else if (g4 == 0) {
    valp[m] = ha[0] + vb[0];
  }
}

extern "C" void kernel_launch(void* const* d_in, const int* in_sizes, int n_in,
                              void* d_out, int out_size, void* d_ws,
                              size_t ws_size, hipStream_t stream) {
  (void)in_sizes; (void)n_in; (void)ws_size; (void)out_size;
  const float* state = (const float*)d_in[0];
  const float* aw1 = (const float*)d_in[1];
  const float* ab1 = (const float*)d_in[2];
  const float* aw2 = (const float*)d_in[3];
  const float* ab2 = (const float*)d_in[4];
  const float* cw1 = (const float*)d_in[5];
  const float* cb1 = (const float*)d_in[6];
  const float* cw2 = (const float*)d_in[7];
  const float* cb2 = (const float*)d_in[8];
  const float* awih = (const float*)d_in[9];
  // d_in[10] = a_whh (unused: zero-state LSTM)
  const float* abih = (const float*)d_in[11];
  const float* abhh = (const float*)d_in[12];
  const float* cwih = (const float*)d_in[13];
  // d_in[14] = c_whh (unused)
  const float* cbih = (const float*)d_in[15];
  const float* cbhh = (const float*)d_in[16];
  const float* mw = (const float*)d_in[17];
  const float* mb = (const float*)d_in[18];
  const float* lw = (const float*)d_in[19];
  const float* lb = (const float*)d_in[20];
  const float* vw = (const float*)d_in[21];
  const float* vb = (const float*)d_in[22];
  char* ws = (char*)d_ws;

  prep_weights<<<dim3(8, 14), 256, 0, stream>>>(
      aw1, aw2, awih, cw1, cw2, cwih, mw, lw, vw, abih, abhh, cbih, cbhh, ws);
  fused_ac<<<8192, 256, 0, stream>>>(state, ab1, ab2, cb1, cb2, mb, lb, vb, ws,
                                     (float*)d_out);
}

// Round 6
// 125.617 us; speedup vs baseline: 4.4795x; 1.0236x over previous
//
#include <hip/hip_runtime.h>

// Fused actor-critic forward for S=256,B=1024,D=64,H=128,A=8.
// R6: weights never touch LDS. Frag-ordered bf16 weight images in ws (prep);
// each wave reads its 32-feat slice per GEMM straight global(L2)->VGPR as one
// contiguous 16B/lane burst per kc. LDS = 16KB activation buffer only
// (X -> H1 -> H2 -> h). Gate GEMMs (i,g,o) run barrier-free (abuf read-only);
// gate math = carry algebra (4 exp2 + 2 rcp / elem) with prescaled biases.
// MLP biases folded into accumulator init. launch_bounds(256,3), 64-row blocks.

#define NROWS (256 * 1024)
#define HID 128
#define ACTD 8

// ws layout (bytes) — all weight images frag-ordered:
// chunk dst = (((ftile*KC + kc)*4 + ks)*16 + r)*16 ; lane addr = base +
// ((ftile*KC+kc)<<10) + ((lane>>4)<<8) + ((lane&15)<<4)
#define W1_OFF 0                  // [128f][64K]  KC=2, 16KB
#define W2_OFF 16384              // [128][128]   KC=4, 32KB
#define WI_OFF 49152              // wih rows 0..127
#define WG_OFF 81920              // wih rows 256..383
#define WO_OFF 114688             // wih rows 384..511
#define PSTR 147456               // per-path stride
#define HEAD_OFF (2 * PSTR)       // actor [mw;lw] 4KB, critic [vw;0] 4KB
#define GB_OFF (HEAD_OFF + 8192)  // prescaled gate biases, 384 f32 per path

#define NEG_L (-1.4426950408889634f)
#define TWO_L (2.8853900817779268f)

typedef __attribute__((ext_vector_type(8))) short s16x8;
typedef __attribute__((ext_vector_type(4))) float fx4;
typedef __attribute__((ext_vector_type(2))) unsigned int u32x2;
typedef __attribute__((ext_vector_type(4))) unsigned int u32x4;

__device__ __forceinline__ unsigned int cvtpk(float lo, float hi) {
  unsigned int r;
  asm("v_cvt_pk_bf16_f32 %0, %1, %2" : "=v"(r) : "v"(lo), "v"(hi));
  return r;
}

__device__ __forceinline__ float ex2(float x) {
  return __builtin_amdgcn_exp2f(x);
}
__device__ __forceinline__ float frcp(float x) {
  return __builtin_amdgcn_rcpf(x);
}

// 8 bf16 from swizzled LDS tile: row-major 2^rowsh B/row, chunk XOR (row&7)<<4
__device__ __forceinline__ s16x8 frag_ld(const unsigned short* base, int row,
                                         int kbyte, int rowsh) {
  int byte = (row << rowsh) + (kbyte ^ ((row & 7) << 4));
  return *(const s16x8*)((const char*)base + byte);
}

__device__ __forceinline__ void zacc(fx4 acc[4][2]) {
#pragma unroll
  for (int j = 0; j < 4; ++j)
#pragma unroll
    for (int i = 0; i < 2; ++i) acc[j][i] = fx4{0.f, 0.f, 0.f, 0.f};
}

// init acc with per-feature bias (broadcast across row tiles)
__device__ __forceinline__ void bacc(fx4 acc[4][2], const float* __restrict__ b,
                                     int fb, int g4) {
#pragma unroll
  for (int it = 0; it < 2; ++it) {
    fx4 bv = *(const fx4*)(b + fb + it * 16 + g4);
#pragma unroll
    for (int jt = 0; jt < 4; ++jt) acc[jt][it] = bv;
  }
}

// Feature-split GEMM, weights straight from global frag-ordered image.
// Wave wv -> feats wv*32..+31, rows 0..63 from swizzled abuf.
template <int KC, int ASH>
__device__ __forceinline__ void gemm_g(const char* __restrict__ wimg,
                                       const unsigned short* at, int wv,
                                       int lane, fx4 acc[4][2]) {
  const int l15 = lane & 15;
  const int kb0 = (lane >> 4) << 4;
  const int woff = ((lane >> 4) << 8) + (l15 << 4);
#pragma unroll
  for (int kc = 0; kc < KC; ++kc) {
    int kbyte = kc * 64 + kb0;
    s16x8 w0 = *(const s16x8*)(wimg + (((wv * 2 + 0) * KC + kc) << 10) + woff);
    s16x8 w1 = *(const s16x8*)(wimg + (((wv * 2 + 1) * KC + kc) << 10) + woff);
#pragma unroll
    for (int jt = 0; jt < 4; ++jt) {
      s16x8 a = frag_ld(at, jt * 16 + l15, kbyte, ASH);
      acc[jt][0] = __builtin_amdgcn_mfma_f32_16x16x32_bf16(w0, a, acc[jt][0], 0, 0, 0);
      acc[jt][1] = __builtin_amdgcn_mfma_f32_16x16x32_bf16(w1, a, acc[jt][1], 0, 0, 0);
    }
  }
}

// acc (bias already in) -> relu -> bf16 -> swizzled abuf [64][128f] 256B rows
__device__ __forceinline__ void epi_relu(fx4 acc[4][2], unsigned short* obuf,
                                         int fb, int lane) {
  const int g4 = (lane >> 4) << 2;
  const int l15 = lane & 15;
  char* ob = (char*)obuf;
#pragma unroll
  for (int it = 0; it < 2; ++it) {
    int n0 = fb + it * 16 + g4;
#pragma unroll
    for (int jt = 0; jt < 4; ++jt) {
      fx4 v = acc[jt][it];
#pragma unroll
      for (int r = 0; r < 4; ++r) v[r] = fmaxf(v[r], 0.0f);
      u32x2 u;
      u[0] = cvtpk(v[0], v[1]);
      u[1] = cvtpk(v[2], v[3]);
      int m = jt * 16 + l15;
      *(u32x2*)(ob + (m << 8) + ((n0 * 2) ^ ((m & 7) << 4))) = u;
    }
  }
}

// ---------------- prep: weights -> bf16 frag-ordered images ----------------
__global__ void prep_weights(const float* __restrict__ aw1,
                             const float* __restrict__ aw2,
                             const float* __restrict__ awih,
                             const float* __restrict__ cw1,
                             const float* __restrict__ cw2,
                             const float* __restrict__ cwih,
                             const float* __restrict__ mw,
                             const float* __restrict__ lw,
                             const float* __restrict__ vw,
                             const float* __restrict__ abih,
                             const float* __restrict__ abhh,
                             const float* __restrict__ cbih,
                             const float* __restrict__ cbhh,
                             char* __restrict__ ws) {
  int y = blockIdx.y;
  int idx = blockIdx.x * 256 + threadIdx.x;
  if (y >= 12) {  // prescaled gate biases: [pgi(128); pgg(128); pgo(128)]
    if (idx < 384) {
      float* dst = (float*)(ws + GB_OFF + (size_t)(y - 12) * 1536);
      const float* b0 = (y == 12) ? abih : cbih;
      const float* b1 = (y == 12) ? abhh : cbhh;
      int sect = idx >> 7, f = idx & 127;
      int srow = (sect == 0) ? f : (sect == 1) ? 256 + f : 384 + f;
      float scale = (sect == 1) ? TWO_L : NEG_L;
      dst[idx] = scale * (b0[srow] + b1[srow]);
    }
    return;
  }
  if (y >= 10) {  // head images: 16 rows x 128 K, frag-ordered (ftile=0)
    if (idx >= 256) return;
    int row = idx >> 4, c16 = idx & 15, kc = c16 >> 2, ks = c16 & 3;
    fx4 v0 = {0.f, 0.f, 0.f, 0.f}, v1 = v0;
    if (y == 10) {
      const float* src = (row < 8) ? (mw + (size_t)row * HID + c16 * 8)
                                   : (lw + (size_t)(row - 8) * HID + c16 * 8);
      v0 = ((const fx4*)src)[0];
      v1 = ((const fx4*)src)[1];
    } else if (row == 0) {
      const float* src = vw + c16 * 8;
      v0 = ((const fx4*)src)[0];
      v1 = ((const fx4*)src)[1];
    }
    u32x4 u;
    u[0] = cvtpk(v0[0], v0[1]);
    u[1] = cvtpk(v0[2], v0[3]);
    u[2] = cvtpk(v1[0], v1[1]);
    u[3] = cvtpk(v1[2], v1[3]);
    int dst = ((kc * 4 + ks) * 16 + row) * 16;
    *(u32x4*)(ws + HEAD_OFF + (size_t)(y - 10) * 4096 + dst) = u;
    return;
  }
  const float* src;
  int nch, ksh, KC, off;
  switch (y) {
    case 0:  src = aw1;              nch = 1024; ksh = 3; KC = 2; off = W1_OFF;        break;
    case 1:  src = aw2;              nch = 2048; ksh = 4; KC = 4; off = W2_OFF;        break;
    case 2:  src = awih;             nch = 2048; ksh = 4; KC = 4; off = WI_OFF;        break;
    case 3:  src = awih + 256 * HID; nch = 2048; ksh = 4; KC = 4; off = WG_OFF;        break;
    case 4:  src = awih + 384 * HID; nch = 2048; ksh = 4; KC = 4; off = WO_OFF;        break;
    case 5:  src = cw1;              nch = 1024; ksh = 3; KC = 2; off = PSTR + W1_OFF; break;
    case 6:  src = cw2;              nch = 2048; ksh = 4; KC = 4; off = PSTR + W2_OFF; break;
    case 7:  src = cwih;             nch = 2048; ksh = 4; KC = 4; off = PSTR + WI_OFF; break;
    case 8:  src = cwih + 256 * HID; nch = 2048; ksh = 4; KC = 4; off = PSTR + WG_OFF; break;
    default: src = cwih + 384 * HID; nch = 2048; ksh = 4; KC = 4; off = PSTR + WO_OFF; break;
  }
  if (idx >= nch) return;
  int row = idx >> ksh;
  int c16 = idx & ((1 << ksh) - 1);
  int b2 = row >> 4, r = row & 15, kc = c16 >> 2, ks = c16 & 3;
  const fx4* gp = (const fx4*)(src + (size_t)idx * 8);
  fx4 v0 = gp[0], v1 = gp[1];
  u32x4 u;
  u[0] = cvtpk(v0[0], v0[1]);
  u[1] = cvtpk(v0[2], v0[3]);
  u[2] = cvtpk(v1[0], v1[1]);
  u[3] = cvtpk(v1[2], v1[3]);
  int dst = (((b2 * KC + kc) * 4 + ks) * 16 + r) * 16;
  *(u32x4*)(ws + off + dst) = u;
}

// ---------------- main fused kernel: one path x 64 rows per block ----------
__global__ __launch_bounds__(256, 3) void fused_ac(
    const float* __restrict__ state, const float* __restrict__ ab1,
    const float* __restrict__ ab2, const float* __restrict__ cb1,
    const float* __restrict__ cb2, const float* __restrict__ mb,
    const float* __restrict__ lb, const float* __restrict__ vb,
    const char* __restrict__ ws, float* __restrict__ outp) {
  __shared__ __align__(16) unsigned short abuf[8192];  // 16KB: X->H1->H2->h

  const int tid = threadIdx.x;
  const int lane = tid & 63;
  const int wv = tid >> 6;
  const int l15 = lane & 15;
  const int g4 = (lane >> 4) << 2;
  const int kb0 = (lane >> 4) << 4;
  const int fb = wv << 5;  // feature band base
  const int path = blockIdx.x >> 12;
  const int rbase = (blockIdx.x & 4095) << 6;  // 64 rows per block

  const char* wsp = ws + (size_t)path * PSTR;
  const float* b1 = path ? cb1 : ab1;
  const float* b2 = path ? cb2 : ab2;
  const float* gb = (const float*)(ws + GB_OFF + (size_t)path * 1536);
  const char* himg = ws + HEAD_OFF + (size_t)path * 4096;

  float* meanp = outp;
  float* stdp = outp + (size_t)NROWS * ACTD;
  float* valp = outp + (size_t)NROWS * ACTD * 2;

  // stage X [64][64] f32 -> bf16 swizzled (128B rows) into abuf
  {
    const float* xg = state + (size_t)rbase * 64;
    char* ab = (char*)abuf;
#pragma unroll
    for (int i = 0; i < 2; ++i) {
      int idx = tid + i * 256;
      int r = idx >> 3, c = idx & 7;
      const fx4* gp = (const fx4*)(xg + idx * 8);
      fx4 v0 = gp[0], v1 = gp[1];
      u32x4 u;
      u[0] = cvtpk(v0[0], v0[1]);
      u[1] = cvtpk(v0[2], v0[3]);
      u[2] = cvtpk(v1[0], v1[1]);
      u[3] = cvtpk(v1[2], v1[3]);
      *(u32x4*)(ab + r * 128 + ((c << 4) ^ ((r & 7) << 4))) = u;
    }
  }
  __syncthreads();

  fx4 acc[4][2];
  bacc(acc, b1, fb, g4);
  gemm_g<2, 7>(wsp + W1_OFF, abuf, wv, lane, acc);  // H1 = X*W1^T + b1
  __syncthreads();
  epi_relu(acc, abuf, fb, lane);
  __syncthreads();

  bacc(acc, b2, fb, g4);
  gemm_g<4, 8>(wsp + W2_OFF, abuf, wv, lane, acc);  // H2 = H1*W2^T + b2
  __syncthreads();
  epi_relu(acc, abuf, fb, lane);
  __syncthreads();

  // gate GEMMs: abuf read-only -> no barriers between them
  fx4 carry[4][2];  // e^{-i} -> e^{2c}
  zacc(acc);
  gemm_g<4, 8>(wsp + WI_OFF, abuf, wv, lane, acc);  // i gate
#pragma unroll
  for (int it = 0; it < 2; ++it) {
    fx4 pv = *(const fx4*)(gb + fb + it * 16 + g4);
#pragma unroll
    for (int jt = 0; jt < 4; ++jt)
#pragma unroll
      for (int r = 0; r < 4; ++r)
        carry[jt][it][r] = ex2(fmaf(acc[jt][it][r], NEG_L, pv[r]));  // e^{-i}
  }

  zacc(acc);
  gemm_g<4, 8>(wsp + WG_OFF, abuf, wv, lane, acc);  // g gate
#pragma unroll
  for (int it = 0; it < 2; ++it) {
    fx4 pv = *(const fx4*)(gb + 128 + fb + it * 16 + g4);
#pragma unroll
    for (int jt = 0; jt < 4; ++jt)
#pragma unroll
      for (int r = 0; r < 4; ++r) {
        float Eg = ex2(fmaf(acc[jt][it][r], TWO_L, pv[r]));  // e^{2g}
        float c = (Eg - 1.0f) * frcp((Eg + 1.0f) * (carry[jt][it][r] + 1.0f));
        carry[jt][it][r] = ex2(c * TWO_L);  // e^{2c}
      }
  }

  zacc(acc);
  gemm_g<4, 8>(wsp + WO_OFF, abuf, wv, lane, acc);  // o gate
  __syncthreads();  // all gate reads of abuf done; safe to overwrite with h
  {
    char* ob = (char*)abuf;
#pragma unroll
    for (int it = 0; it < 2; ++it) {
      fx4 pv = *(const fx4*)(gb + 256 + fb + it * 16 + g4);
      int n0 = fb + it * 16 + g4;
#pragma unroll
      for (int jt = 0; jt < 4; ++jt) {
        fx4 h;
#pragma unroll
        for (int r = 0; r < 4; ++r) {
          float Eo = ex2(fmaf(acc[jt][it][r], NEG_L, pv[r]));  // e^{-o}
          float Ec = carry[jt][it][r];
          h[r] = (Ec - 1.0f) * frcp((Ec + 1.0f) * (Eo + 1.0f));
        }
        u32x2 u;
        u[0] = cvtpk(h[0], h[1]);
        u[1] = cvtpk(h[2], h[3]);
        int m = jt * 16 + l15;
        *(u32x2*)(ob + (m << 8) + ((n0 * 2) ^ ((m & 7) << 4))) = u;
      }
    }
  }
  __syncthreads();

  // head GEMM: wave wv -> rows wv*16..+15; head weights from global image
  fx4 ha = fx4{0.f, 0.f, 0.f, 0.f};
  const int woff = ((lane >> 4) << 8) + (l15 << 4);
#pragma unroll
  for (int kc = 0; kc < 4; ++kc) {
    s16x8 w = *(const s16x8*)(himg + (kc << 10) + woff);
    s16x8 a = frag_ld(abuf, (wv << 4) + l15, kc * 64 + kb0, 8);
    ha = __builtin_amdgcn_mfma_f32_16x16x32_bf16(w, a, ha, 0, 0, 0);
  }

  int m = rbase + (wv << 4) + l15;
  if (path == 0) {
    if (g4 < 8) {
      fx4 v = ha + *(const fx4*)(mb + g4);
      *(fx4*)(meanp + (size_t)m * ACTD + g4) = v;
    } else {
      fx4 v;
#pragma unroll
      for (int r = 0; r < 4; ++r) v[r] = __expf(ha[r] + lb[g4 - 8 + r]);
      *(fx4*)(stdp + (size_t)m * ACTD + (g4 - 8)) = v;
    }
  } else if (g4 == 0) {
    valp[m] = ha[0] + vb[0];
  }
}

extern "C" void kernel_launch(void* const* d_in, const int* in_sizes, int n_in,
                              void* d_out, int out_size, void* d_ws,
                              size_t ws_size, hipStream_t stream) {
  (void)in_sizes; (void)n_in; (void)ws_size; (void)out_size;
  const float* state = (const float*)d_in[0];
  const float* aw1 = (const float*)d_in[1];
  const float* ab1 = (const float*)d_in[2];
  const float* aw2 = (const float*)d_in[3];
  const float* ab2 = (const float*)d_in[4];
  const float* cw1 = (const float*)d_in[5];
  const float* cb1 = (const float*)d_in[6];
  const float* cw2 = (const float*)d_in[7];
  const float* cb2 = (const float*)d_in[8];
  const float* awih = (const float*)d_in[9];
  // d_in[10] = a_whh (unused: zero-state LSTM)
  const float* abih = (const float*)d_in[11];
  const float* abhh = (const float*)d_in[12];
  const float* cwih = (const float*)d_in[13];
  // d_in[14] = c_whh (unused)
  const float* cbih = (const float*)d_in[15];
  const float* cbhh = (const float*)d_in[16];
  const float* mw = (const float*)d_in[17];
  const float* mb = (const float*)d_in[18];
  const float* lw = (const float*)d_in[19];
  const float* lb = (const float*)d_in[20];
  const float* vw = (const float*)d_in[21];
  const float* vb = (const float*)d_in[22];
  char* ws = (char*)d_ws;

  prep_weights<<<dim3(8, 14), 256, 0, stream>>>(
      aw1, aw2, awih, cw1, cw2, cwih, mw, lw, vw, abih, abhh, cbih, cbhh, ws);
  fused_ac<<<8192, 256, 0, stream>>>(state, ab1, ab2, cb1, cb2, mb, lb, vb, ws,
                                     (float*)d_out);
}